// Round 1
// baseline (724.600 us; speedup 1.0000x reference)
//
#include <hip/hip_runtime.h>

#define NN 100000
#define NE 1600000
#define D 128
#define BN_EPS 1e-5f

static __device__ __forceinline__ float frelu(float x){ return x > 0.f ? x : 0.f; }

// ---------------- init: zero counters + BN partial sums ----------------
__global__ void k_init(int* __restrict__ cnt, int* __restrict__ fill, float* __restrict__ colsum){
  int i = blockIdx.x*256 + threadIdx.x;
  if (i < NN){ cnt[i] = 0; fill[i] = 0; }
  if (i < 2*D) colsum[i] = 0.f;
}

// ---------------- in-degree count (dst row of edge_index) ----------------
__global__ void k_count(const int* __restrict__ ei, int* __restrict__ cnt){
  int e = blockIdx.x*256 + threadIdx.x;
  if (e < NE) atomicAdd(&cnt[ei[NE + e]], 1);
}

// dinv[i] = rsqrt(deg), deg = in-degree + 1 self-loop (always > 0)
__global__ void k_dinv(const int* __restrict__ cnt, float* __restrict__ dinv){
  int i = blockIdx.x*256 + threadIdx.x;
  if (i < NN) dinv[i] = rsqrtf((float)(cnt[i] + 1));
}

// ---------------- 3-pass exclusive scan of cnt -> rowStart ----------------
__global__ void k_scanA(const int* __restrict__ cnt, int* __restrict__ bsum){
  __shared__ int lds[256];
  int tid = threadIdx.x;
  int base = blockIdx.x*1024 + tid*4;
  int s = 0;
  #pragma unroll
  for (int j = 0; j < 4; j++){ int idx = base + j; if (idx < NN) s += cnt[idx]; }
  lds[tid] = s; __syncthreads();
  for (int off = 128; off > 0; off >>= 1){
    if (tid < off) lds[tid] += lds[tid + off];
    __syncthreads();
  }
  if (tid == 0) bsum[blockIdx.x] = lds[0];
}

__global__ void k_scanB(int* __restrict__ bsum, int nb){
  __shared__ int lds[128];
  int tid = threadIdx.x;
  int v = (tid < nb) ? bsum[tid] : 0;
  lds[tid] = v; __syncthreads();
  for (int off = 1; off < 128; off <<= 1){
    int t = (tid >= off) ? lds[tid - off] : 0;
    __syncthreads();
    lds[tid] += t;
    __syncthreads();
  }
  if (tid < nb) bsum[tid] = lds[tid] - v;  // exclusive
}

__global__ void k_scanC(const int* __restrict__ cnt, const int* __restrict__ bsum, int* __restrict__ rowStart){
  __shared__ int lds[256];
  int tid = threadIdx.x;
  int base = blockIdx.x*1024 + tid*4;
  int v[4]; int s = 0;
  #pragma unroll
  for (int j = 0; j < 4; j++){ int idx = base + j; v[j] = (idx < NN) ? cnt[idx] : 0; s += v[j]; }
  lds[tid] = s; __syncthreads();
  for (int off = 1; off < 256; off <<= 1){
    int t = (tid >= off) ? lds[tid - off] : 0;
    __syncthreads();
    lds[tid] += t;
    __syncthreads();
  }
  int ex = lds[tid] - s + bsum[blockIdx.x];
  #pragma unroll
  for (int j = 0; j < 4; j++){ int idx = base + j; if (idx < NN) rowStart[idx] = ex; ex += v[j]; }
}

// ---------------- CSR fill: colIdx[rowStart[dst] + k] = src ----------------
__global__ void k_fill(const int* __restrict__ ei, const int* __restrict__ rowStart,
                       int* __restrict__ fill, int* __restrict__ colIdx){
  int e = blockIdx.x*256 + threadIdx.x;
  if (e < NE){
    int s = ei[e];
    int d = ei[NE + e];
    int pos = rowStart[d] + atomicAdd(&fill[d], 1);
    colIdx[pos] = s;
  }
}

// ---------------- GEMM: H[N][128] = X[N][128] @ W[128][128], f32 ----------------
// W staged in LDS (64KB -> 2 blocks/CU). 64 rows/block, per-thread 4 rows x 8 cols
// (cols c0..c0+3 and c0+64..c0+67 -> 2-way LDS bank aliasing, free).
__global__ __launch_bounds__(256, 2) void k_gemm(const float* __restrict__ X,
                                                 const float* __restrict__ Wm,
                                                 float* __restrict__ H){
  __shared__ float ws[D][D];
  int tid = threadIdx.x;
  {
    const float4* W4 = (const float4*)Wm;
    float4* S4 = (float4*)ws;
    #pragma unroll
    for (int i = 0; i < 16; i++) S4[tid + i*256] = W4[tid + i*256];
  }
  __syncthreads();

  int cg = tid & 15, rg = tid >> 4;
  int row0 = blockIdx.x*64 + rg*4;
  int c0 = cg*4;

  float acc[4][8];
  #pragma unroll
  for (int i = 0; i < 4; i++)
    #pragma unroll
    for (int j = 0; j < 8; j++) acc[i][j] = 0.f;

  int r[4];
  #pragma unroll
  for (int i = 0; i < 4; i++){ int rr = row0 + i; r[i] = (rr < NN) ? rr : (NN - 1); }

  const float4* X4 = (const float4*)X;
  for (int k0 = 0; k0 < D; k0 += 4){
    float4 xv[4];
    #pragma unroll
    for (int i = 0; i < 4; i++) xv[i] = X4[r[i]*(D/4) + (k0 >> 2)];
    #pragma unroll
    for (int kk = 0; kk < 4; kk++){
      float4 w1 = *(const float4*)&ws[k0 + kk][c0];
      float4 w2 = *(const float4*)&ws[k0 + kk][c0 + 64];
      #pragma unroll
      for (int i = 0; i < 4; i++){
        float xf = (kk == 0) ? xv[i].x : (kk == 1) ? xv[i].y : (kk == 2) ? xv[i].z : xv[i].w;
        acc[i][0] += xf*w1.x; acc[i][1] += xf*w1.y; acc[i][2] += xf*w1.z; acc[i][3] += xf*w1.w;
        acc[i][4] += xf*w2.x; acc[i][5] += xf*w2.y; acc[i][6] += xf*w2.z; acc[i][7] += xf*w2.w;
      }
    }
  }

  #pragma unroll
  for (int i = 0; i < 4; i++){
    int rr = row0 + i;
    if (rr < NN){
      *(float4*)&H[rr*D + c0]      = make_float4(acc[i][0], acc[i][1], acc[i][2], acc[i][3]);
      *(float4*)&H[rr*D + c0 + 64] = make_float4(acc[i][4], acc[i][5], acc[i][6], acc[i][7]);
    }
  }
}

// ---------------- aggregate: one wave per dst node, gather h[src] ----------------
// agg[i] = dinv[i] * ( dinv[i]*h[i] + sum_{s in inlist(i)} dinv[s]*h[s] )
__global__ __launch_bounds__(256) void k_agg(const float* __restrict__ H,
                                             const float* __restrict__ dinv,
                                             const int* __restrict__ rowStart,
                                             const int* __restrict__ cnt,
                                             const int* __restrict__ colIdx,
                                             float* __restrict__ out){
  int node = blockIdx.x*4 + (threadIdx.x >> 6);
  if (node >= NN) return;
  int lane = threadIdx.x & 63;
  const float2* Hp = (const float2*)H;
  float di = dinv[node];
  float2 acc = Hp[(size_t)node*64 + lane];
  acc.x *= di; acc.y *= di;
  int beg = rowStart[node];
  int n = cnt[node];
  for (int j = 0; j < n; j++){
    int s = colIdx[beg + j];
    float ds = dinv[s];
    float2 v = Hp[(size_t)s*64 + lane];
    acc.x += ds*v.x; acc.y += ds*v.y;
  }
  acc.x *= di; acc.y *= di;
  ((float2*)out)[(size_t)node*64 + lane] = acc;
}

// ---------------- BN column sums (sum, sumsq) ----------------
__global__ void k_bnreduce(const float* __restrict__ A, float* __restrict__ colsum){
  int tid = threadIdx.x;
  int c = tid & (D - 1);
  int half = tid >> 7;  // 0 or 1
  float s = 0.f, sq = 0.f;
  for (int r = blockIdx.x*2 + half; r < NN; r += gridDim.x*2){
    float v = A[(size_t)r*D + c];
    s += v; sq += v*v;
  }
  __shared__ float lds[256];
  lds[tid] = s; __syncthreads();
  if (half == 0) s += lds[tid + 128];
  __syncthreads();
  lds[tid] = sq; __syncthreads();
  if (half == 0){
    sq += lds[tid + 128];
    atomicAdd(&colsum[c], s);
    atomicAdd(&colsum[D + c], sq);
  }
}

// mu/rstd, then zero the partial sums for the next layer/call
__global__ void k_bnfinal(float* __restrict__ colsum, float* __restrict__ murstd){
  int c = threadIdx.x;
  float mu = colsum[c] * (1.f / NN);
  float var = colsum[D + c] * (1.f / NN) - mu*mu;
  murstd[c] = mu;
  murstd[D + c] = rsqrtf(var + BN_EPS);
  colsum[c] = 0.f; colsum[D + c] = 0.f;
}

// ---------------- BN apply + ReLU, in place ----------------
__global__ void k_bnapply(float* __restrict__ A, const float* __restrict__ ms,
                          const float* __restrict__ gamma, const float* __restrict__ beta){
  int idx = blockIdx.x*256 + threadIdx.x;
  if (idx < NN*D/4){
    float4 v = ((float4*)A)[idx];
    int c = (idx*4) & (D - 1);
    float o[4] = {v.x, v.y, v.z, v.w};
    #pragma unroll
    for (int j = 0; j < 4; j++){
      float mu = ms[c + j], rs = ms[D + c + j];
      o[j] = frelu(gamma[c + j]*((o[j] - mu)*rs) + beta[c + j]);
    }
    ((float4*)A)[idx] = make_float4(o[0], o[1], o[2], o[3]);
  }
}

extern "C" void kernel_launch(void* const* d_in, const int* in_sizes, int n_in,
                              void* d_out, int out_size, void* d_ws, size_t ws_size,
                              hipStream_t stream){
  const float* x   = (const float*)d_in[0];
  const int*   ei  = (const int*)d_in[1];   // [2][NE], row0 = src, row1 = dst
  const float* W1  = (const float*)d_in[2];
  const float* g1  = (const float*)d_in[4];
  const float* be1 = (const float*)d_in[5];
  const float* W2  = (const float*)d_in[6];
  const float* g2  = (const float*)d_in[8];
  const float* be2 = (const float*)d_in[9];
  // b1/b2 cancel exactly inside BatchNorm (agg+b - mean(agg+b)) -> skipped.

  float* out = (float*)d_out;
  float* o1 = out;
  float* o2 = out + (size_t)NN*D;

  char* ws = (char*)d_ws;
  int*   cnt      = (int*)(ws + 0);          // 400000 B
  int*   fill     = (int*)(ws + 400384);     // 400000 B
  int*   rowStart = (int*)(ws + 800768);     // 400004 B
  int*   bsum     = (int*)(ws + 1201408);    // 512 B
  float* dinv     = (float*)(ws + 1202176);  // 400000 B
  float* colsum   = (float*)(ws + 1602560);  // 1024 B (sum | sumsq)
  float* murstd   = (float*)(ws + 1603584);  // 1024 B (mu | rstd)
  int*   colIdx   = (int*)(ws + 1604608);    // 6.4 MB
  float* h        = (float*)(ws + 8004864);  // 51.2 MB
  // total ~59.3 MB of ws

  int nbScan = (NN + 1023)/1024;  // 98

  k_init <<<(NN + 255)/256, 256, 0, stream>>>(cnt, fill, colsum);
  k_count<<<(NE + 255)/256, 256, 0, stream>>>(ei, cnt);
  k_dinv <<<(NN + 255)/256, 256, 0, stream>>>(cnt, dinv);
  k_scanA<<<nbScan, 256, 0, stream>>>(cnt, bsum);
  k_scanB<<<1, 128, 0, stream>>>(bsum, nbScan);
  k_scanC<<<nbScan, 256, 0, stream>>>(cnt, bsum, rowStart);
  k_fill <<<(NE + 255)/256, 256, 0, stream>>>(ei, rowStart, fill, colIdx);

  // ---- layer 1 ----
  k_gemm    <<<(NN + 63)/64, 256, 0, stream>>>(x, W1, h);
  k_agg     <<<(NN + 3)/4, 256, 0, stream>>>(h, dinv, rowStart, cnt, colIdx, o1);
  k_bnreduce<<<512, 256, 0, stream>>>(o1, colsum);
  k_bnfinal <<<1, 128, 0, stream>>>(colsum, murstd);
  k_bnapply <<<(NN*D/4 + 255)/256, 256, 0, stream>>>(o1, murstd, g1, be1);

  // ---- layer 2 ----
  k_gemm    <<<(NN + 63)/64, 256, 0, stream>>>(o1, W2, h);
  k_agg     <<<(NN + 3)/4, 256, 0, stream>>>(h, dinv, rowStart, cnt, colIdx, o2);
  k_bnreduce<<<512, 256, 0, stream>>>(o2, colsum);
  k_bnfinal <<<1, 128, 0, stream>>>(colsum, murstd);
  k_bnapply <<<(NN*D/4 + 255)/256, 256, 0, stream>>>(o2, murstd, g2, be2);
}

// Round 2
// 544.359 us; speedup vs baseline: 1.3311x; 1.3311x over previous
//
#include <hip/hip_runtime.h>

#define NN 100000
#define NE 1600000
#define D 128
#define BN_EPS 1e-5f

static __device__ __forceinline__ float frelu(float x){ return x > 0.f ? x : 0.f; }

// bf16 helpers (RNE pack, cheap unpack)
static __device__ __forceinline__ unsigned short f2bf(float f){
  unsigned int u = __float_as_uint(f);
  u += 0x7fffu + ((u >> 16) & 1u);
  return (unsigned short)(u >> 16);
}
static __device__ __forceinline__ float bflo(unsigned int p){ return __uint_as_float(p << 16); }
static __device__ __forceinline__ float bfhi(unsigned int p){ return __uint_as_float(p & 0xffff0000u); }

// ---------------- init: zero counters + BN partial sums ----------------
__global__ void k_init(int* __restrict__ cnt, int* __restrict__ fill, float* __restrict__ colsum){
  int i = blockIdx.x*256 + threadIdx.x;
  if (i < NN){ cnt[i] = 0; fill[i] = 0; }
  if (i < 2*D) colsum[i] = 0.f;
}

// ---------------- in-degree count (dst row of edge_index) ----------------
__global__ void k_count(const int* __restrict__ ei, int* __restrict__ cnt){
  int e = blockIdx.x*256 + threadIdx.x;
  if (e < NE) atomicAdd(&cnt[ei[NE + e]], 1);
}

// dinv[i] = rsqrt(deg), deg = in-degree + 1 self-loop (always > 0)
__global__ void k_dinv(const int* __restrict__ cnt, float* __restrict__ dinv){
  int i = blockIdx.x*256 + threadIdx.x;
  if (i < NN) dinv[i] = rsqrtf((float)(cnt[i] + 1));
}

// ---------------- 3-pass exclusive scan of cnt -> rowStart ----------------
__global__ void k_scanA(const int* __restrict__ cnt, int* __restrict__ bsum){
  __shared__ int lds[256];
  int tid = threadIdx.x;
  int base = blockIdx.x*1024 + tid*4;
  int s = 0;
  #pragma unroll
  for (int j = 0; j < 4; j++){ int idx = base + j; if (idx < NN) s += cnt[idx]; }
  lds[tid] = s; __syncthreads();
  for (int off = 128; off > 0; off >>= 1){
    if (tid < off) lds[tid] += lds[tid + off];
    __syncthreads();
  }
  if (tid == 0) bsum[blockIdx.x] = lds[0];
}

__global__ void k_scanB(int* __restrict__ bsum, int nb){
  __shared__ int lds[128];
  int tid = threadIdx.x;
  int v = (tid < nb) ? bsum[tid] : 0;
  lds[tid] = v; __syncthreads();
  for (int off = 1; off < 128; off <<= 1){
    int t = (tid >= off) ? lds[tid - off] : 0;
    __syncthreads();
    lds[tid] += t;
    __syncthreads();
  }
  if (tid < nb) bsum[tid] = lds[tid] - v;  // exclusive
}

__global__ void k_scanC(const int* __restrict__ cnt, const int* __restrict__ bsum, int* __restrict__ rowStart){
  __shared__ int lds[256];
  int tid = threadIdx.x;
  int base = blockIdx.x*1024 + tid*4;
  int v[4]; int s = 0;
  #pragma unroll
  for (int j = 0; j < 4; j++){ int idx = base + j; v[j] = (idx < NN) ? cnt[idx] : 0; s += v[j]; }
  lds[tid] = s; __syncthreads();
  for (int off = 1; off < 256; off <<= 1){
    int t = (tid >= off) ? lds[tid - off] : 0;
    __syncthreads();
    lds[tid] += t;
    __syncthreads();
  }
  int ex = lds[tid] - s + bsum[blockIdx.x];
  #pragma unroll
  for (int j = 0; j < 4; j++){ int idx = base + j; if (idx < NN) rowStart[idx] = ex; ex += v[j]; }
}

// ---------------- CSR fill: colIdx[rowStart[dst] + k] = src ----------------
__global__ void k_fill(const int* __restrict__ ei, const int* __restrict__ rowStart,
                       int* __restrict__ fill, int* __restrict__ colIdx){
  int e = blockIdx.x*256 + threadIdx.x;
  if (e < NE){
    int s = ei[e];
    int d = ei[NE + e];
    int pos = rowStart[d] + atomicAdd(&fill[d], 1);
    colIdx[pos] = s;
  }
}

// ---------------- GEMM: H[N][128] = X[N][128] @ W[128][128], f32 in, bf16 out ----
// W staged in LDS (64KB -> 2 blocks/CU). 64 rows/block, per-thread 4 rows x 8 cols
// (cols c0..c0+3 and c0+64..c0+67 -> 2-way LDS bank aliasing, free).
__global__ __launch_bounds__(256, 2) void k_gemm(const float* __restrict__ X,
                                                 const float* __restrict__ Wm,
                                                 unsigned short* __restrict__ H){
  __shared__ float ws[D][D];
  int tid = threadIdx.x;
  {
    const float4* W4 = (const float4*)Wm;
    float4* S4 = (float4*)ws;
    #pragma unroll
    for (int i = 0; i < 16; i++) S4[tid + i*256] = W4[tid + i*256];
  }
  __syncthreads();

  int cg = tid & 15, rg = tid >> 4;
  int row0 = blockIdx.x*64 + rg*4;
  int c0 = cg*4;

  float acc[4][8];
  #pragma unroll
  for (int i = 0; i < 4; i++)
    #pragma unroll
    for (int j = 0; j < 8; j++) acc[i][j] = 0.f;

  int r[4];
  #pragma unroll
  for (int i = 0; i < 4; i++){ int rr = row0 + i; r[i] = (rr < NN) ? rr : (NN - 1); }

  const float4* X4 = (const float4*)X;
  for (int k0 = 0; k0 < D; k0 += 4){
    float4 xv[4];
    #pragma unroll
    for (int i = 0; i < 4; i++) xv[i] = X4[r[i]*(D/4) + (k0 >> 2)];
    #pragma unroll
    for (int kk = 0; kk < 4; kk++){
      float4 w1 = *(const float4*)&ws[k0 + kk][c0];
      float4 w2 = *(const float4*)&ws[k0 + kk][c0 + 64];
      #pragma unroll
      for (int i = 0; i < 4; i++){
        float xf = (kk == 0) ? xv[i].x : (kk == 1) ? xv[i].y : (kk == 2) ? xv[i].z : xv[i].w;
        acc[i][0] += xf*w1.x; acc[i][1] += xf*w1.y; acc[i][2] += xf*w1.z; acc[i][3] += xf*w1.w;
        acc[i][4] += xf*w2.x; acc[i][5] += xf*w2.y; acc[i][6] += xf*w2.z; acc[i][7] += xf*w2.w;
      }
    }
  }

  #pragma unroll
  for (int i = 0; i < 4; i++){
    int rr = row0 + i;
    if (rr < NN){
      ushort4 p1 = make_ushort4(f2bf(acc[i][0]), f2bf(acc[i][1]), f2bf(acc[i][2]), f2bf(acc[i][3]));
      ushort4 p2 = make_ushort4(f2bf(acc[i][4]), f2bf(acc[i][5]), f2bf(acc[i][6]), f2bf(acc[i][7]));
      *(ushort4*)&H[(size_t)rr*D + c0]      = p1;
      *(ushort4*)&H[(size_t)rr*D + c0 + 64] = p2;
    }
  }
}

// ---------------- aggregate: one wave per dst node, gather bf16 h[src] --------
// agg[i] = dinv[i] * ( dinv[i]*h[i] + sum_{s in inlist(i)} dinv[s]*h[s] )
// Lane owns columns (2*lane, 2*lane+1) as one packed u32. Edge loop unrolled x4
// with independent accumulators for memory-level parallelism.
__global__ __launch_bounds__(256) void k_agg(const unsigned int* __restrict__ Hp,
                                             const float* __restrict__ dinv,
                                             const int* __restrict__ rowStart,
                                             const int* __restrict__ cnt,
                                             const int* __restrict__ colIdx,
                                             float* __restrict__ out){
  int node = blockIdx.x*4 + (threadIdx.x >> 6);
  if (node >= NN) return;
  int lane = threadIdx.x & 63;
  float di = dinv[node];
  unsigned int self = Hp[(size_t)node*64 + lane];

  float a0x = 0.f, a0y = 0.f, a1x = 0.f, a1y = 0.f;
  float a2x = 0.f, a2y = 0.f, a3x = 0.f, a3y = 0.f;

  int beg = rowStart[node];
  int n = cnt[node];
  int j = 0;
  for (; j + 4 <= n; j += 4){
    int s0 = colIdx[beg + j];
    int s1 = colIdx[beg + j + 1];
    int s2 = colIdx[beg + j + 2];
    int s3 = colIdx[beg + j + 3];
    float e0 = dinv[s0], e1 = dinv[s1], e2 = dinv[s2], e3 = dinv[s3];
    unsigned int v0 = Hp[(size_t)s0*64 + lane];
    unsigned int v1 = Hp[(size_t)s1*64 + lane];
    unsigned int v2 = Hp[(size_t)s2*64 + lane];
    unsigned int v3 = Hp[(size_t)s3*64 + lane];
    a0x += e0*bflo(v0); a0y += e0*bfhi(v0);
    a1x += e1*bflo(v1); a1y += e1*bfhi(v1);
    a2x += e2*bflo(v2); a2y += e2*bfhi(v2);
    a3x += e3*bflo(v3); a3y += e3*bfhi(v3);
  }
  for (; j < n; j++){
    int s = colIdx[beg + j];
    float e = dinv[s];
    unsigned int v = Hp[(size_t)s*64 + lane];
    a0x += e*bflo(v); a0y += e*bfhi(v);
  }

  float sx = (a0x + a1x) + (a2x + a3x);
  float sy = (a0y + a1y) + (a2y + a3y);
  sx += di*bflo(self);
  sy += di*bfhi(self);
  float2 res = make_float2(di*sx, di*sy);
  ((float2*)out)[(size_t)node*64 + lane] = res;
}

// ---------------- BN column sums (sum, sumsq) ----------------
__global__ void k_bnreduce(const float* __restrict__ A, float* __restrict__ colsum){
  int tid = threadIdx.x;
  int c = tid & (D - 1);
  int half = tid >> 7;  // 0 or 1
  float s = 0.f, sq = 0.f;
  for (int r = blockIdx.x*2 + half; r < NN; r += gridDim.x*2){
    float v = A[(size_t)r*D + c];
    s += v; sq += v*v;
  }
  __shared__ float lds[256];
  lds[tid] = s; __syncthreads();
  if (half == 0) s += lds[tid + 128];
  __syncthreads();
  lds[tid] = sq; __syncthreads();
  if (half == 0){
    sq += lds[tid + 128];
    atomicAdd(&colsum[c], s);
    atomicAdd(&colsum[D + c], sq);
  }
}

// mu/rstd, then zero the partial sums for the next layer/call
__global__ void k_bnfinal(float* __restrict__ colsum, float* __restrict__ murstd){
  int c = threadIdx.x;
  float mu = colsum[c] * (1.f / NN);
  float var = colsum[D + c] * (1.f / NN) - mu*mu;
  murstd[c] = mu;
  murstd[D + c] = rsqrtf(var + BN_EPS);
  colsum[c] = 0.f; colsum[D + c] = 0.f;
}

// ---------------- BN apply + ReLU, in place ----------------
__global__ void k_bnapply(float* __restrict__ A, const float* __restrict__ ms,
                          const float* __restrict__ gamma, const float* __restrict__ beta){
  int idx = blockIdx.x*256 + threadIdx.x;
  if (idx < NN*D/4){
    float4 v = ((float4*)A)[idx];
    int c = (idx*4) & (D - 1);
    float o[4] = {v.x, v.y, v.z, v.w};
    #pragma unroll
    for (int j = 0; j < 4; j++){
      float mu = ms[c + j], rs = ms[D + c + j];
      o[j] = frelu(gamma[c + j]*((o[j] - mu)*rs) + beta[c + j]);
    }
    ((float4*)A)[idx] = make_float4(o[0], o[1], o[2], o[3]);
  }
}

extern "C" void kernel_launch(void* const* d_in, const int* in_sizes, int n_in,
                              void* d_out, int out_size, void* d_ws, size_t ws_size,
                              hipStream_t stream){
  const float* x   = (const float*)d_in[0];
  const int*   ei  = (const int*)d_in[1];   // [2][NE], row0 = src, row1 = dst
  const float* W1  = (const float*)d_in[2];
  const float* g1  = (const float*)d_in[4];
  const float* be1 = (const float*)d_in[5];
  const float* W2  = (const float*)d_in[6];
  const float* g2  = (const float*)d_in[8];
  const float* be2 = (const float*)d_in[9];
  // b1/b2 cancel exactly inside BatchNorm (agg+b - mean(agg+b)) -> skipped.

  float* out = (float*)d_out;
  float* o1 = out;
  float* o2 = out + (size_t)NN*D;

  char* ws = (char*)d_ws;
  int*   cnt      = (int*)(ws + 0);          // 400000 B
  int*   fill     = (int*)(ws + 400384);     // 400000 B
  int*   rowStart = (int*)(ws + 800768);     // 400004 B
  int*   bsum     = (int*)(ws + 1201408);    // 512 B
  float* dinv     = (float*)(ws + 1202176);  // 400000 B
  float* colsum   = (float*)(ws + 1602560);  // 1024 B (sum | sumsq)
  float* murstd   = (float*)(ws + 1603584);  // 1024 B (mu | rstd)
  int*   colIdx   = (int*)(ws + 1604608);    // 6.4 MB
  unsigned short* h = (unsigned short*)(ws + 8004864);  // 25.6 MB (bf16 H)
  // total ~33.7 MB of ws

  int nbScan = (NN + 1023)/1024;  // 98

  k_init <<<(NN + 255)/256, 256, 0, stream>>>(cnt, fill, colsum);
  k_count<<<(NE + 255)/256, 256, 0, stream>>>(ei, cnt);
  k_dinv <<<(NN + 255)/256, 256, 0, stream>>>(cnt, dinv);
  k_scanA<<<nbScan, 256, 0, stream>>>(cnt, bsum);
  k_scanB<<<1, 128, 0, stream>>>(bsum, nbScan);
  k_scanC<<<nbScan, 256, 0, stream>>>(cnt, bsum, rowStart);
  k_fill <<<(NE + 255)/256, 256, 0, stream>>>(ei, rowStart, fill, colIdx);

  // ---- layer 1 ----
  k_gemm    <<<(NN + 63)/64, 256, 0, stream>>>(x, W1, h);
  k_agg     <<<(NN + 3)/4, 256, 0, stream>>>((const unsigned int*)h, dinv, rowStart, cnt, colIdx, o1);
  k_bnreduce<<<512, 256, 0, stream>>>(o1, colsum);
  k_bnfinal <<<1, 128, 0, stream>>>(colsum, murstd);
  k_bnapply <<<(NN*D/4 + 255)/256, 256, 0, stream>>>(o1, murstd, g1, be1);

  // ---- layer 2 ----
  k_gemm    <<<(NN + 63)/64, 256, 0, stream>>>(o1, W2, h);
  k_agg     <<<(NN + 3)/4, 256, 0, stream>>>((const unsigned int*)h, dinv, rowStart, cnt, colIdx, o2);
  k_bnreduce<<<512, 256, 0, stream>>>(o2, colsum);
  k_bnfinal <<<1, 128, 0, stream>>>(colsum, murstd);
  k_bnapply <<<(NN*D/4 + 255)/256, 256, 0, stream>>>(o2, murstd, g2, be2);
}

// Round 3
// 456.768 us; speedup vs baseline: 1.5864x; 1.1918x over previous
//
#include <hip/hip_runtime.h>

#define NN 100000
#define NE 1600000
#define D 128
#define BN_EPS 1e-5f

#define NB 782        // ceil(NN / 128) buckets, bucket = dst >> 7
#define NWG_BIN 200   // workgroups in hist/scatter passes
#define CHUNK 8000    // NE / NWG_BIN, exact

static __device__ __forceinline__ float frelu(float x){ return x > 0.f ? x : 0.f; }

// bf16 helpers (RNE pack, cheap unpack)
static __device__ __forceinline__ unsigned short f2bf(float f){
  unsigned int u = __float_as_uint(f);
  u += 0x7fffu + ((u >> 16) & 1u);
  return (unsigned short)(u >> 16);
}
static __device__ __forceinline__ float bflo(unsigned int p){ return __uint_as_float(p << 16); }
static __device__ __forceinline__ float bfhi(unsigned int p){ return __uint_as_float(p & 0xffff0000u); }

// ---------------- zero BN partial sums ----------------
__global__ void k_init(float* __restrict__ colsum){
  int i = threadIdx.x;
  if (i < 2*D) colsum[i] = 0.f;
}

// ---------------- CSR build, pass 1: per-WG bucket histogram (LDS only) ------
__global__ __launch_bounds__(256) void kb_hist(const int* __restrict__ ei, int* __restrict__ wgHist){
  __shared__ int hist[NB];
  int tid = threadIdx.x, w = blockIdx.x;
  for (int i = tid; i < NB; i += 256) hist[i] = 0;
  __syncthreads();
  int base = w*CHUNK;
  for (int e = base + tid; e < base + CHUNK; e += 256)
    atomicAdd(&hist[ei[NE + e] >> 7], 1);
  __syncthreads();
  for (int i = tid; i < NB; i += 256) wgHist[w*NB + i] = hist[i];
}

// ---- pass 2a: for each bucket, exclusive scan across WGs + bucket totals ----
__global__ __launch_bounds__(256) void kb_scan(int* __restrict__ wgHist, int* __restrict__ bucketTotal){
  __shared__ int lds[256];
  int b = blockIdx.x, t = threadIdx.x;
  int v = (t < NWG_BIN) ? wgHist[t*NB + b] : 0;
  lds[t] = v; __syncthreads();
  for (int off = 1; off < 256; off <<= 1){
    int u = (t >= off) ? lds[t - off] : 0;
    __syncthreads(); lds[t] += u; __syncthreads();
  }
  if (t < NWG_BIN) wgHist[t*NB + b] = lds[t] - v;  // exclusive along w
  if (t == 255) bucketTotal[b] = lds[255];
}

// ---- pass 2b: exclusive scan of bucket totals -> bucketStart[0..NB] ---------
__global__ __launch_bounds__(256) void kb_scan2(const int* __restrict__ bucketTotal, int* __restrict__ bucketStart){
  __shared__ int lds[256];
  int t = threadIdx.x;
  int v[4]; int s = 0;
  #pragma unroll
  for (int j = 0; j < 4; j++){ int i = t*4 + j; v[j] = (i < NB) ? bucketTotal[i] : 0; s += v[j]; }
  lds[t] = s; __syncthreads();
  for (int off = 1; off < 256; off <<= 1){
    int u = (t >= off) ? lds[t - off] : 0;
    __syncthreads(); lds[t] += u; __syncthreads();
  }
  int ex = lds[t] - s;
  #pragma unroll
  for (int j = 0; j < 4; j++){ int i = t*4 + j; if (i <= NB) bucketStart[i] = ex; ex += v[j]; }
}

// ---- pass 3: scatter edges into bucket-sorted array (reserved ranges) -------
__global__ __launch_bounds__(256) void kb_scatter(const int* __restrict__ ei, const int* __restrict__ wgHist,
                                                  const int* __restrict__ bucketStart, uint2* __restrict__ binned){
  __shared__ int fillB[NB];
  __shared__ int baseB[NB];
  int tid = threadIdx.x, w = blockIdx.x;
  for (int i = tid; i < NB; i += 256){ fillB[i] = 0; baseB[i] = bucketStart[i] + wgHist[w*NB + i]; }
  __syncthreads();
  int base = w*CHUNK;
  for (int e = base + tid; e < base + CHUNK; e += 256){
    int s = ei[e], d = ei[NE + e];
    int b = d >> 7;
    int r = atomicAdd(&fillB[b], 1);
    binned[baseB[b] + r] = make_uint2((unsigned)s, (unsigned)d);
  }
}

// ---- pass 4: per-bucket (128 nodes) -> cnt, rowStart, dinv, colIdx ----------
__global__ __launch_bounds__(256) void kb_node(const uint2* __restrict__ binned, const int* __restrict__ bucketStart,
                                               int* __restrict__ cnt, int* __restrict__ rowStart,
                                               float* __restrict__ dinv, int* __restrict__ colIdx){
  __shared__ int ncnt[128], roff[128], nfill[128];
  int b = blockIdx.x, t = threadIdx.x;
  int s0 = bucketStart[b], s1 = bucketStart[b + 1];
  int node0 = b << 7;
  int nNodes = min(128, NN - node0);
  if (t < 128){ ncnt[t] = 0; nfill[t] = 0; }
  __syncthreads();
  for (int e = s0 + t; e < s1; e += 256)
    atomicAdd(&ncnt[binned[e].y & 127], 1);
  __syncthreads();
  if (t < 128) roff[t] = ncnt[t];
  __syncthreads();
  for (int off = 1; off < 128; off <<= 1){
    int u = (t >= off && t < 128) ? roff[t - off] : 0;
    __syncthreads(); if (t < 128) roff[t] += u; __syncthreads();
  }
  // roff = inclusive scan; exclusive = roff[i] - ncnt[i]
  if (t < nNodes){
    int ex = roff[t] - ncnt[t];
    rowStart[node0 + t] = s0 + ex;
    cnt[node0 + t] = ncnt[t];
    dinv[node0 + t] = rsqrtf((float)(ncnt[t] + 1));
  }
  __syncthreads();
  for (int e = s0 + t; e < s1; e += 256){
    uint2 ed = binned[e];
    int l = ed.y & 127;
    int r = atomicAdd(&nfill[l], 1);
    colIdx[s0 + (roff[l] - ncnt[l]) + r] = (int)ed.x;
  }
}

// ---------------- GEMM: H[N][128] = X[N][128] @ W[128][128], f32 in, bf16 out ----
__global__ __launch_bounds__(256, 2) void k_gemm(const float* __restrict__ X,
                                                 const float* __restrict__ Wm,
                                                 unsigned short* __restrict__ H){
  __shared__ float ws[D][D];
  int tid = threadIdx.x;
  {
    const float4* W4 = (const float4*)Wm;
    float4* S4 = (float4*)ws;
    #pragma unroll
    for (int i = 0; i < 16; i++) S4[tid + i*256] = W4[tid + i*256];
  }
  __syncthreads();

  int cg = tid & 15, rg = tid >> 4;
  int row0 = blockIdx.x*64 + rg*4;
  int c0 = cg*4;

  float acc[4][8];
  #pragma unroll
  for (int i = 0; i < 4; i++)
    #pragma unroll
    for (int j = 0; j < 8; j++) acc[i][j] = 0.f;

  int r[4];
  #pragma unroll
  for (int i = 0; i < 4; i++){ int rr = row0 + i; r[i] = (rr < NN) ? rr : (NN - 1); }

  const float4* X4 = (const float4*)X;
  for (int k0 = 0; k0 < D; k0 += 4){
    float4 xv[4];
    #pragma unroll
    for (int i = 0; i < 4; i++) xv[i] = X4[r[i]*(D/4) + (k0 >> 2)];
    #pragma unroll
    for (int kk = 0; kk < 4; kk++){
      float4 w1 = *(const float4*)&ws[k0 + kk][c0];
      float4 w2 = *(const float4*)&ws[k0 + kk][c0 + 64];
      #pragma unroll
      for (int i = 0; i < 4; i++){
        float xf = (kk == 0) ? xv[i].x : (kk == 1) ? xv[i].y : (kk == 2) ? xv[i].z : xv[i].w;
        acc[i][0] += xf*w1.x; acc[i][1] += xf*w1.y; acc[i][2] += xf*w1.z; acc[i][3] += xf*w1.w;
        acc[i][4] += xf*w2.x; acc[i][5] += xf*w2.y; acc[i][6] += xf*w2.z; acc[i][7] += xf*w2.w;
      }
    }
  }

  #pragma unroll
  for (int i = 0; i < 4; i++){
    int rr = row0 + i;
    if (rr < NN){
      ushort4 p1 = make_ushort4(f2bf(acc[i][0]), f2bf(acc[i][1]), f2bf(acc[i][2]), f2bf(acc[i][3]));
      ushort4 p2 = make_ushort4(f2bf(acc[i][4]), f2bf(acc[i][5]), f2bf(acc[i][6]), f2bf(acc[i][7]));
      *(ushort4*)&H[(size_t)rr*D + c0]      = p1;
      *(ushort4*)&H[(size_t)rr*D + c0 + 64] = p2;
    }
  }
}

// ---------------- aggregate: one wave per dst node, gather bf16 h[src] --------
__global__ __launch_bounds__(256) void k_agg(const unsigned int* __restrict__ Hp,
                                             const float* __restrict__ dinv,
                                             const int* __restrict__ rowStart,
                                             const int* __restrict__ cnt,
                                             const int* __restrict__ colIdx,
                                             float* __restrict__ out){
  int node = blockIdx.x*4 + (threadIdx.x >> 6);
  if (node >= NN) return;
  int lane = threadIdx.x & 63;
  float di = dinv[node];
  unsigned int self = Hp[(size_t)node*64 + lane];

  float a0x = 0.f, a0y = 0.f, a1x = 0.f, a1y = 0.f;
  float a2x = 0.f, a2y = 0.f, a3x = 0.f, a3y = 0.f;

  int beg = rowStart[node];
  int n = cnt[node];
  int j = 0;
  for (; j + 4 <= n; j += 4){
    int s0 = colIdx[beg + j];
    int s1 = colIdx[beg + j + 1];
    int s2 = colIdx[beg + j + 2];
    int s3 = colIdx[beg + j + 3];
    float e0 = dinv[s0], e1 = dinv[s1], e2 = dinv[s2], e3 = dinv[s3];
    unsigned int v0 = Hp[(size_t)s0*64 + lane];
    unsigned int v1 = Hp[(size_t)s1*64 + lane];
    unsigned int v2 = Hp[(size_t)s2*64 + lane];
    unsigned int v3 = Hp[(size_t)s3*64 + lane];
    a0x += e0*bflo(v0); a0y += e0*bfhi(v0);
    a1x += e1*bflo(v1); a1y += e1*bfhi(v1);
    a2x += e2*bflo(v2); a2y += e2*bfhi(v2);
    a3x += e3*bflo(v3); a3y += e3*bfhi(v3);
  }
  for (; j < n; j++){
    int s = colIdx[beg + j];
    float e = dinv[s];
    unsigned int v = Hp[(size_t)s*64 + lane];
    a0x += e*bflo(v); a0y += e*bfhi(v);
  }

  float sx = (a0x + a1x) + (a2x + a3x);
  float sy = (a0y + a1y) + (a2y + a3y);
  sx += di*bflo(self);
  sy += di*bfhi(self);
  float2 res = make_float2(di*sx, di*sy);
  ((float2*)out)[(size_t)node*64 + lane] = res;
}

// ---------------- BN column sums (sum, sumsq) ----------------
__global__ void k_bnreduce(const float* __restrict__ A, float* __restrict__ colsum){
  int tid = threadIdx.x;
  int c = tid & (D - 1);
  int half = tid >> 7;  // 0 or 1
  float s = 0.f, sq = 0.f;
  for (int r = blockIdx.x*2 + half; r < NN; r += gridDim.x*2){
    float v = A[(size_t)r*D + c];
    s += v; sq += v*v;
  }
  __shared__ float lds[256];
  lds[tid] = s; __syncthreads();
  if (half == 0) s += lds[tid + 128];
  __syncthreads();
  lds[tid] = sq; __syncthreads();
  if (half == 0){
    sq += lds[tid + 128];
    atomicAdd(&colsum[c], s);
    atomicAdd(&colsum[D + c], sq);
  }
}

// mu/rstd, then zero the partial sums for the next layer/call
__global__ void k_bnfinal(float* __restrict__ colsum, float* __restrict__ murstd){
  int c = threadIdx.x;
  float mu = colsum[c] * (1.f / NN);
  float var = colsum[D + c] * (1.f / NN) - mu*mu;
  murstd[c] = mu;
  murstd[D + c] = rsqrtf(var + BN_EPS);
  colsum[c] = 0.f; colsum[D + c] = 0.f;
}

// ---------------- BN apply + ReLU, in place ----------------
__global__ void k_bnapply(float* __restrict__ A, const float* __restrict__ ms,
                          const float* __restrict__ gamma, const float* __restrict__ beta){
  int idx = blockIdx.x*256 + threadIdx.x;
  if (idx < NN*D/4){
    float4 v = ((float4*)A)[idx];
    int c = (idx*4) & (D - 1);
    float o[4] = {v.x, v.y, v.z, v.w};
    #pragma unroll
    for (int j = 0; j < 4; j++){
      float mu = ms[c + j], rs = ms[D + c + j];
      o[j] = frelu(gamma[c + j]*((o[j] - mu)*rs) + beta[c + j]);
    }
    ((float4*)A)[idx] = make_float4(o[0], o[1], o[2], o[3]);
  }
}

extern "C" void kernel_launch(void* const* d_in, const int* in_sizes, int n_in,
                              void* d_out, int out_size, void* d_ws, size_t ws_size,
                              hipStream_t stream){
  const float* x   = (const float*)d_in[0];
  const int*   ei  = (const int*)d_in[1];   // [2][NE], row0 = src, row1 = dst
  const float* W1  = (const float*)d_in[2];
  const float* g1  = (const float*)d_in[4];
  const float* be1 = (const float*)d_in[5];
  const float* W2  = (const float*)d_in[6];
  const float* g2  = (const float*)d_in[8];
  const float* be2 = (const float*)d_in[9];
  // b1/b2 cancel exactly inside BatchNorm (agg+b - mean(agg+b)) -> skipped.

  float* out = (float*)d_out;
  float* o1 = out;
  float* o2 = out + (size_t)NN*D;

  char* ws = (char*)d_ws;
  int*   cnt         = (int*)(ws + 0);          // 400000 B
  int*   rowStart    = (int*)(ws + 400384);     // 400000 B
  float* dinv        = (float*)(ws + 800896);   // 400000 B
  float* colsum      = (float*)(ws + 1201152);  // 1024 B
  float* murstd      = (float*)(ws + 1202176);  // 1024 B
  int*   bucketTotal = (int*)(ws + 1203200);    // 3128 B
  int*   bucketStart = (int*)(ws + 1206400);    // 3132 B
  int*   wgHist      = (int*)(ws + 1209600);    // 625600 B
  int*   colIdx      = (int*)(ws + 1835200);    // 6.4 MB
  uint2* binned      = (uint2*)(ws + 8235200);  // 12.8 MB
  unsigned short* h  = (unsigned short*)(ws + 21035200);  // 25.6 MB (bf16 H)
  // total ~46.6 MB of ws

  // ---- graph preprocessing: LDS-privatized 2-level counting sort ----
  k_init    <<<1, 256, 0, stream>>>(colsum);
  kb_hist   <<<NWG_BIN, 256, 0, stream>>>(ei, wgHist);
  kb_scan   <<<NB, 256, 0, stream>>>(wgHist, bucketTotal);
  kb_scan2  <<<1, 256, 0, stream>>>(bucketTotal, bucketStart);
  kb_scatter<<<NWG_BIN, 256, 0, stream>>>(ei, wgHist, bucketStart, binned);
  kb_node   <<<NB, 256, 0, stream>>>(binned, bucketStart, cnt, rowStart, dinv, colIdx);

  // ---- layer 1 ----
  k_gemm    <<<(NN + 63)/64, 256, 0, stream>>>(x, W1, h);
  k_agg     <<<(NN + 3)/4, 256, 0, stream>>>((const unsigned int*)h, dinv, rowStart, cnt, colIdx, o1);
  k_bnreduce<<<512, 256, 0, stream>>>(o1, colsum);
  k_bnfinal <<<1, 128, 0, stream>>>(colsum, murstd);
  k_bnapply <<<(NN*D/4 + 255)/256, 256, 0, stream>>>(o1, murstd, g1, be1);

  // ---- layer 2 ----
  k_gemm    <<<(NN + 63)/64, 256, 0, stream>>>(o1, W2, h);
  k_agg     <<<(NN + 3)/4, 256, 0, stream>>>((const unsigned int*)h, dinv, rowStart, cnt, colIdx, o2);
  k_bnreduce<<<512, 256, 0, stream>>>(o2, colsum);
  k_bnfinal <<<1, 128, 0, stream>>>(colsum, murstd);
  k_bnapply <<<(NN*D/4 + 255)/256, 256, 0, stream>>>(o2, murstd, g2, be2);
}

// Round 4
// 349.407 us; speedup vs baseline: 2.0738x; 1.3073x over previous
//
#include <hip/hip_runtime.h>

#define NN 100000
#define NE 1600000
#define D 128
#define BN_EPS 1e-5f

#define NB 782        // ceil(NN / 128) buckets, bucket = dst >> 7
#define NWG_BIN 200   // workgroups in hist/scatter passes
#define CHUNK 8000    // NE / NWG_BIN, exact

typedef __attribute__((ext_vector_type(4))) _Float16 f16x4;
typedef __attribute__((ext_vector_type(4))) float f32x4;

static __device__ __forceinline__ float frelu(float x){ return x > 0.f ? x : 0.f; }

// bf16 helpers (RNE pack, cheap unpack)
static __device__ __forceinline__ unsigned short f2bf(float f){
  unsigned int u = __float_as_uint(f);
  u += 0x7fffu + ((u >> 16) & 1u);
  return (unsigned short)(u >> 16);
}
static __device__ __forceinline__ float bflo(unsigned int p){ return __uint_as_float(p << 16); }
static __device__ __forceinline__ float bfhi(unsigned int p){ return __uint_as_float(p & 0xffff0000u); }

// ---------------- zero BN partial sums ----------------
__global__ void k_init(float* __restrict__ colsum){
  int i = threadIdx.x;
  if (i < 2*D) colsum[i] = 0.f;
}

// ---------------- pack W (f32 row-major [k][n]) into f16 MFMA B-fragment order ----
// slot s = (nt*8+kt)*64 + lane holds 4 f16: W[kt*16 + 4*(lane>>4) + j][nt*16 + (lane&15)]
__global__ __launch_bounds__(256) void k_wprep(const float* __restrict__ W1f, const float* __restrict__ W2f,
                                               unsigned long long* __restrict__ P1, unsigned long long* __restrict__ P2){
  const float* W = blockIdx.x ? W2f : W1f;
  unsigned long long* P = blockIdx.x ? P2 : P1;
  int t = threadIdx.x;
  for (int i = 0; i < 16; i++){
    int s = t*16 + i;
    int l = s & 63, kt = (s >> 6) & 7, nt = s >> 9;
    int krow = kt*16 + ((l >> 4) << 2);
    int col = nt*16 + (l & 15);
    f16x4 v;
    #pragma unroll
    for (int j = 0; j < 4; j++) v[j] = (_Float16)W[(krow + j)*D + col];
    P[s] = __builtin_bit_cast(unsigned long long, v);
  }
}

// ---------------- CSR build, pass 1: per-WG bucket histogram (LDS only) ------
__global__ __launch_bounds__(256) void kb_hist(const int* __restrict__ ei, int* __restrict__ wgHist){
  __shared__ int hist[NB];
  int tid = threadIdx.x, w = blockIdx.x;
  for (int i = tid; i < NB; i += 256) hist[i] = 0;
  __syncthreads();
  int base = w*CHUNK;
  for (int e = base + tid; e < base + CHUNK; e += 256)
    atomicAdd(&hist[ei[NE + e] >> 7], 1);
  __syncthreads();
  for (int i = tid; i < NB; i += 256) wgHist[w*NB + i] = hist[i];
}

// ---- pass 2a: for each bucket, exclusive scan across WGs + bucket totals ----
__global__ __launch_bounds__(256) void kb_scan(int* __restrict__ wgHist, int* __restrict__ bucketTotal){
  __shared__ int lds[256];
  int b = blockIdx.x, t = threadIdx.x;
  int v = (t < NWG_BIN) ? wgHist[t*NB + b] : 0;
  lds[t] = v; __syncthreads();
  for (int off = 1; off < 256; off <<= 1){
    int u = (t >= off) ? lds[t - off] : 0;
    __syncthreads(); lds[t] += u; __syncthreads();
  }
  if (t < NWG_BIN) wgHist[t*NB + b] = lds[t] - v;  // exclusive along w
  if (t == 255) bucketTotal[b] = lds[255];
}

// ---- pass 2b: exclusive scan of bucket totals -> bucketStart[0..NB] ---------
__global__ __launch_bounds__(256) void kb_scan2(const int* __restrict__ bucketTotal, int* __restrict__ bucketStart){
  __shared__ int lds[256];
  int t = threadIdx.x;
  int v[4]; int s = 0;
  #pragma unroll
  for (int j = 0; j < 4; j++){ int i = t*4 + j; v[j] = (i < NB) ? bucketTotal[i] : 0; s += v[j]; }
  lds[t] = s; __syncthreads();
  for (int off = 1; off < 256; off <<= 1){
    int u = (t >= off) ? lds[t - off] : 0;
    __syncthreads(); lds[t] += u; __syncthreads();
  }
  int ex = lds[t] - s;
  #pragma unroll
  for (int j = 0; j < 4; j++){ int i = t*4 + j; if (i <= NB) bucketStart[i] = ex; ex += v[j]; }
}

// ---- pass 3: scatter edges into bucket-sorted array; pack (src<<7)|(dst&127) ----
__global__ __launch_bounds__(256) void kb_scatter(const int* __restrict__ ei, const int* __restrict__ wgHist,
                                                  const int* __restrict__ bucketStart, unsigned int* __restrict__ binned){
  __shared__ int fillB[NB];
  __shared__ int baseB[NB];
  int tid = threadIdx.x, w = blockIdx.x;
  for (int i = tid; i < NB; i += 256){ fillB[i] = 0; baseB[i] = bucketStart[i] + wgHist[w*NB + i]; }
  __syncthreads();
  int base = w*CHUNK;
  for (int e = base + tid; e < base + CHUNK; e += 256){
    int s = ei[e], d = ei[NE + e];
    int b = d >> 7;
    int r = atomicAdd(&fillB[b], 1);
    binned[baseB[b] + r] = ((unsigned)s << 7) | (unsigned)(d & 127);
  }
}

// ---- pass 4: per-bucket (128 nodes) -> cnt, rowStart, dinv, colIdx ----------
__global__ __launch_bounds__(256) void kb_node(const unsigned int* __restrict__ binned, const int* __restrict__ bucketStart,
                                               int* __restrict__ cnt, int* __restrict__ rowStart,
                                               float* __restrict__ dinv, int* __restrict__ colIdx){
  __shared__ int ncnt[128], roff[128], nfill[128];
  int b = blockIdx.x, t = threadIdx.x;
  int s0 = bucketStart[b], s1 = bucketStart[b + 1];
  int node0 = b << 7;
  int nNodes = min(128, NN - node0);
  if (t < 128){ ncnt[t] = 0; nfill[t] = 0; }
  __syncthreads();
  for (int e = s0 + t; e < s1; e += 256)
    atomicAdd(&ncnt[binned[e] & 127], 1);
  __syncthreads();
  if (t < 128) roff[t] = ncnt[t];
  __syncthreads();
  for (int off = 1; off < 128; off <<= 1){
    int u = (t >= off && t < 128) ? roff[t - off] : 0;
    __syncthreads(); if (t < 128) roff[t] += u; __syncthreads();
  }
  if (t < nNodes){
    int ex = roff[t] - ncnt[t];
    rowStart[node0 + t] = s0 + ex;
    cnt[node0 + t] = ncnt[t];
    dinv[node0 + t] = rsqrtf((float)(ncnt[t] + 1));
  }
  __syncthreads();
  for (int e = s0 + t; e < s1; e += 256){
    unsigned int ed = binned[e];
    int l = ed & 127;
    int r = atomicAdd(&nfill[l], 1);
    colIdx[s0 + (roff[l] - ncnt[l]) + r] = (int)(ed >> 7);
  }
}

// ---------------- GEMM via MFMA: H[r] = bf16( dinv[r] * (X[r] @ W) ) ------------
// 4 waves/block, wave owns 16 rows. B-frags loaded from pre-packed Wpk (L2-hot).
__global__ __launch_bounds__(256) void k_gemm(const float* __restrict__ X,
                                              const unsigned long long* __restrict__ Wpk,
                                              const float* __restrict__ dinv,
                                              unsigned short* __restrict__ H){
  int tid = threadIdx.x, lane = tid & 63;
  int row0 = blockIdx.x*64 + (tid >> 6)*16;
  int arow = row0 + (lane & 15); if (arow >= NN) arow = NN - 1;
  int kg = lane >> 4;  // 0..3

  const float4* X4 = (const float4*)X;
  f16x4 a[8];
  #pragma unroll
  for (int kt = 0; kt < 8; kt++){
    float4 xv = X4[(size_t)arow*32 + kt*4 + kg];
    f16x4 av;
    av[0] = (_Float16)xv.x; av[1] = (_Float16)xv.y;
    av[2] = (_Float16)xv.z; av[3] = (_Float16)xv.w;
    a[kt] = av;
  }

  f32x4 acc[8];
  #pragma unroll
  for (int nt = 0; nt < 8; nt++){ acc[nt][0] = 0.f; acc[nt][1] = 0.f; acc[nt][2] = 0.f; acc[nt][3] = 0.f; }

  #pragma unroll
  for (int kt = 0; kt < 8; kt++){
    #pragma unroll
    for (int nt = 0; nt < 8; nt++){
      f16x4 b = __builtin_bit_cast(f16x4, Wpk[(nt*8 + kt)*64 + lane]);
      acc[nt] = __builtin_amdgcn_mfma_f32_16x16x16f16(a[kt], b, acc[nt], 0, 0, 0);
    }
  }

  int rbase = row0 + kg*4;
  float4 dv = *(const float4*)&dinv[rbase];
  #pragma unroll
  for (int r = 0; r < 4; r++){
    int row = rbase + r;
    if (row < NN){
      float sc = (r == 0) ? dv.x : (r == 1) ? dv.y : (r == 2) ? dv.z : dv.w;
      #pragma unroll
      for (int nt = 0; nt < 8; nt++)
        H[(size_t)row*D + nt*16 + (lane & 15)] = f2bf(acc[nt][r]*sc);
    }
  }
}

// ---------------- aggregate: one wave per dst node, gather bf16 rows ----------
// H rows already scaled by dinv[src]; out_bf16[i] = bf16( dinv[i] * (H[i] + sum H[s]) )
__global__ __launch_bounds__(256) void k_agg(const unsigned int* __restrict__ Hp,
                                             const float* __restrict__ dinv,
                                             const int* __restrict__ rowStart,
                                             const int* __restrict__ cnt,
                                             const int* __restrict__ colIdx,
                                             unsigned int* __restrict__ outb){
  int node = blockIdx.x*4 + (threadIdx.x >> 6);
  if (node >= NN) return;
  int lane = threadIdx.x & 63;
  float di = dinv[node];

  unsigned int sv = Hp[(size_t)node*64 + lane];   // self (includes its dinv)
  float x0 = bflo(sv), y0 = bfhi(sv);
  float x1=0.f,y1=0.f,x2=0.f,y2=0.f,x3=0.f,y3=0.f;
  float x4=0.f,y4=0.f,x5=0.f,y5=0.f,x6=0.f,y6=0.f,x7=0.f,y7=0.f;

  int beg = rowStart[node];
  int n = cnt[node];
  int j = 0;
  for (; j + 8 <= n; j += 8){
    int s0 = colIdx[beg+j  ], s1 = colIdx[beg+j+1], s2 = colIdx[beg+j+2], s3 = colIdx[beg+j+3];
    int s4 = colIdx[beg+j+4], s5 = colIdx[beg+j+5], s6 = colIdx[beg+j+6], s7 = colIdx[beg+j+7];
    unsigned int v0 = Hp[(size_t)s0*64 + lane];
    unsigned int v1 = Hp[(size_t)s1*64 + lane];
    unsigned int v2 = Hp[(size_t)s2*64 + lane];
    unsigned int v3 = Hp[(size_t)s3*64 + lane];
    unsigned int v4 = Hp[(size_t)s4*64 + lane];
    unsigned int v5 = Hp[(size_t)s5*64 + lane];
    unsigned int v6 = Hp[(size_t)s6*64 + lane];
    unsigned int v7 = Hp[(size_t)s7*64 + lane];
    x0 += bflo(v0); y0 += bfhi(v0);
    x1 += bflo(v1); y1 += bfhi(v1);
    x2 += bflo(v2); y2 += bfhi(v2);
    x3 += bflo(v3); y3 += bfhi(v3);
    x4 += bflo(v4); y4 += bfhi(v4);
    x5 += bflo(v5); y5 += bfhi(v5);
    x6 += bflo(v6); y6 += bfhi(v6);
    x7 += bflo(v7); y7 += bfhi(v7);
  }
  if (j + 4 <= n){
    int s0 = colIdx[beg+j], s1 = colIdx[beg+j+1], s2 = colIdx[beg+j+2], s3 = colIdx[beg+j+3];
    unsigned int v0 = Hp[(size_t)s0*64 + lane];
    unsigned int v1 = Hp[(size_t)s1*64 + lane];
    unsigned int v2 = Hp[(size_t)s2*64 + lane];
    unsigned int v3 = Hp[(size_t)s3*64 + lane];
    x0 += bflo(v0); y0 += bfhi(v0);
    x1 += bflo(v1); y1 += bfhi(v1);
    x2 += bflo(v2); y2 += bfhi(v2);
    x3 += bflo(v3); y3 += bfhi(v3);
    j += 4;
  }
  for (; j < n; j++){
    int s = colIdx[beg + j];
    unsigned int v = Hp[(size_t)s*64 + lane];
    x0 += bflo(v); y0 += bfhi(v);
  }

  float sx = (x0 + x1) + (x2 + x3) + (x4 + x5) + (x6 + x7);
  float sy = (y0 + y1) + (y2 + y3) + (y4 + y5) + (y6 + y7);
  unsigned int pk = (unsigned int)f2bf(di*sx) | ((unsigned int)f2bf(di*sy) << 16);
  outb[(size_t)node*64 + lane] = pk;
}

// ---------------- BN column sums over bf16 agg ----------------
__global__ __launch_bounds__(256) void k_bnreduce(const unsigned int* __restrict__ A, float* __restrict__ colsum){
  int tid = threadIdx.x;
  int c2 = tid & 63;   // column pair (2c2, 2c2+1)
  int rg = tid >> 6;   // 0..3
  float slo = 0.f, shi = 0.f, qlo = 0.f, qhi = 0.f;
  for (int r = blockIdx.x*4 + rg; r < NN; r += gridDim.x*4){
    unsigned int v = A[(size_t)r*64 + c2];
    float lo = bflo(v), hi = bfhi(v);
    slo += lo; shi += hi; qlo += lo*lo; qhi += hi*hi;
  }
  __shared__ float2 lds[256];
  lds[tid] = make_float2(slo, qlo); __syncthreads();
  if (rg == 0){
    float2 b = lds[c2 + 64], c = lds[c2 + 128], d = lds[c2 + 192];
    atomicAdd(&colsum[2*c2],     slo + b.x + c.x + d.x);
    atomicAdd(&colsum[D + 2*c2], qlo + b.y + c.y + d.y);
  }
  __syncthreads();
  lds[tid] = make_float2(shi, qhi); __syncthreads();
  if (rg == 0){
    float2 b = lds[c2 + 64], c = lds[c2 + 128], d = lds[c2 + 192];
    atomicAdd(&colsum[2*c2 + 1],     shi + b.x + c.x + d.x);
    atomicAdd(&colsum[D + 2*c2 + 1], qhi + b.y + c.y + d.y);
  }
}

// mu/rstd -> folded gb/bb, then zero partial sums for next layer/call
__global__ void k_bnfinal(float* __restrict__ colsum, const float* __restrict__ gamma,
                          const float* __restrict__ beta, float* __restrict__ gb, float* __restrict__ bb){
  int c = threadIdx.x;
  float mu = colsum[c] * (1.f / NN);
  float var = colsum[D + c] * (1.f / NN) - mu*mu;
  float g = gamma[c] * rsqrtf(var + BN_EPS);
  gb[c] = g;
  bb[c] = beta[c] - mu*g;
  colsum[c] = 0.f; colsum[D + c] = 0.f;
}

// ---------------- BN apply + ReLU: bf16 agg -> f32 out ----------------
__global__ __launch_bounds__(256) void k_bnapply(const unsigned int* __restrict__ A, const float* __restrict__ gb,
                                                 const float* __restrict__ bb, float* __restrict__ out){
  int idx = blockIdx.x*256 + threadIdx.x;
  if (idx >= NN*64) return;
  unsigned int v = A[idx];
  int c2 = idx & 63;
  float2 g = ((const float2*)gb)[c2];
  float2 b = ((const float2*)bb)[c2];
  float lo = frelu(bflo(v)*g.x + b.x);
  float hi = frelu(bfhi(v)*g.y + b.y);
  ((float2*)out)[idx] = make_float2(lo, hi);
}

extern "C" void kernel_launch(void* const* d_in, const int* in_sizes, int n_in,
                              void* d_out, int out_size, void* d_ws, size_t ws_size,
                              hipStream_t stream){
  const float* x   = (const float*)d_in[0];
  const int*   ei  = (const int*)d_in[1];   // [2][NE], row0 = src, row1 = dst
  const float* W1  = (const float*)d_in[2];
  const float* g1  = (const float*)d_in[4];
  const float* be1 = (const float*)d_in[5];
  const float* W2  = (const float*)d_in[6];
  const float* g2  = (const float*)d_in[8];
  const float* be2 = (const float*)d_in[9];
  // b1/b2 cancel exactly inside BatchNorm (agg+b - mean(agg+b)) -> skipped.

  float* out = (float*)d_out;
  float* o1 = out;
  float* o2 = out + (size_t)NN*D;

  char* ws = (char*)d_ws;
  int*   cnt         = (int*)(ws + 0);          // 400000 B
  int*   rowStart    = (int*)(ws + 400384);     // 400000 B
  float* dinv        = (float*)(ws + 800768);   // 400000 B (+pad for f4 tail reads)
  float* colsum      = (float*)(ws + 1201152);  // 1024 B
  float* gb          = (float*)(ws + 1202176);  // 512 B
  float* bb          = (float*)(ws + 1202688);  // 512 B
  int*   bucketTotal = (int*)(ws + 1203200);    // 3128 B
  int*   bucketStart = (int*)(ws + 1206400);    // 3132 B
  int*   wgHist      = (int*)(ws + 1209600);    // 625600 B
  unsigned long long* Wpk1 = (unsigned long long*)(ws + 1835264);  // 32768 B
  unsigned long long* Wpk2 = (unsigned long long*)(ws + 1868288);  // 32768 B
  int*   colIdx      = (int*)(ws + 1901312);    // 6.4 MB
  unsigned int* binned = (unsigned int*)(ws + 8301312);   // 6.4 MB (packed src<<7|dstlow)
  unsigned int* aggb = (unsigned int*)(ws + 14701312);    // 25.6 MB (bf16 agg)
  unsigned short* h  = (unsigned short*)(ws + 40301312);  // 25.6 MB (bf16 H)
  // total ~65.9 MB of ws

  // ---- prep: W fragment packing + graph counting-sort ----
  k_init    <<<1, 256, 0, stream>>>(colsum);
  k_wprep   <<<2, 256, 0, stream>>>(W1, W2, Wpk1, Wpk2);
  kb_hist   <<<NWG_BIN, 256, 0, stream>>>(ei, wgHist);
  kb_scan   <<<NB, 256, 0, stream>>>(wgHist, bucketTotal);
  kb_scan2  <<<1, 256, 0, stream>>>(bucketTotal, bucketStart);
  kb_scatter<<<NWG_BIN, 256, 0, stream>>>(ei, wgHist, bucketStart, binned);
  kb_node   <<<NB, 256, 0, stream>>>(binned, bucketStart, cnt, rowStart, dinv, colIdx);

  // ---- layer 1 ----
  k_gemm    <<<(NN + 63)/64, 256, 0, stream>>>(x, Wpk1, dinv, h);
  k_agg     <<<(NN + 3)/4, 256, 0, stream>>>((const unsigned int*)h, dinv, rowStart, cnt, colIdx, aggb);
  k_bnreduce<<<512, 256, 0, stream>>>(aggb, colsum);
  k_bnfinal <<<1, 128, 0, stream>>>(colsum, g1, be1, gb, bb);
  k_bnapply <<<(NN*64 + 255)/256, 256, 0, stream>>>(aggb, gb, bb, o1);

  // ---- layer 2 ----
  k_gemm    <<<(NN + 63)/64, 256, 0, stream>>>(o1, Wpk2, dinv, h);
  k_agg     <<<(NN + 3)/4, 256, 0, stream>>>((const unsigned int*)h, dinv, rowStart, cnt, colIdx, aggb);
  k_bnreduce<<<512, 256, 0, stream>>>(aggb, colsum);
  k_bnfinal <<<1, 128, 0, stream>>>(colsum, g2, be2, gb, bb);
  k_bnapply <<<(NN*64 + 255)/256, 256, 0, stream>>>(aggb, gb, bb, o2);
}